// Round 1
// baseline (511.055 us; speedup 1.0000x reference)
//
#include <hip/hip_runtime.h>
#include <hip/hip_bf16.h>
#include <stdint.h>

typedef short  s16x8 __attribute__((ext_vector_type(8)));
typedef float  f32x4 __attribute__((ext_vector_type(4)));
typedef unsigned short u16;

#define HD 4096   // Hadamard / K dimension

// ---------------------------------------------------------------------------
// Kernel 1: row-wise FWHT (== x @ H for symmetric Sylvester H) + act fake-quant
// One block per row of x. 4096 f32 in LDS, 12 butterfly stages.
// q = rint(clip((xr/64 + beta)/alpha, -8, 7)) stored as bf16 (exact small int),
// plus per-row sum of q (for the beta correction terms in the epilogue).
// ---------------------------------------------------------------------------
__global__ __launch_bounds__(256) void fwht_actq(
    const float* __restrict__ x, const float* __restrict__ alpha,
    const float* __restrict__ beta, u16* __restrict__ qx,
    float* __restrict__ Sx)
{
  __shared__ float s[HD];
  const int row = blockIdx.x;
  const int t = threadIdx.x;

  const float4* xin = (const float4*)(x + (size_t)row * HD);
  float4* s4 = (float4*)s;
  #pragma unroll
  for (int c = 0; c < 4; ++c) s4[c * 256 + t] = xin[c * 256 + t];
  __syncthreads();

  for (int h = 1; h < HD; h <<= 1) {
    #pragma unroll
    for (int p = 0; p < 8; ++p) {
      int pid = p * 256 + t;
      int i = ((pid & ~(h - 1)) << 1) | (pid & (h - 1));
      int j = i + h;
      float a = s[i], b = s[j];
      s[i] = a + b;
      s[j] = a - b;
    }
    __syncthreads();
  }

  const float al = alpha[0];
  const float be = beta[0];
  float qsum = 0.f;
  #pragma unroll
  for (int c = 0; c < 4; ++c) {
    int e = c * 1024 + t * 4;
    float4 v = *(const float4*)(s + e);
    u16 st[4];
    float vv[4] = {v.x, v.y, v.z, v.w};
    #pragma unroll
    for (int k = 0; k < 4; ++k) {
      float xv = vv[k] * 0.015625f + be;   // /sqrt(4096) is exact pow2
      float tq = xv / al;
      tq = fminf(fmaxf(tq, -8.f), 7.f);
      float qq = rintf(tq);                // half-to-even == np.round
      qsum += qq;
      st[k] = (u16)(__float_as_uint(qq) >> 16);  // exact bf16 of small int
    }
    *(ushort4*)(qx + (size_t)row * HD + e) = make_ushort4(st[0], st[1], st[2], st[3]);
  }

  __syncthreads();
  s[t] = qsum;
  __syncthreads();
  for (int o = 128; o > 0; o >>= 1) {
    if (t < o) s[t] += s[t + o];
    __syncthreads();
  }
  if (t == 0) Sx[row] = s[0];
}

// ---------------------------------------------------------------------------
// Kernel 2: weight fake-quant (learnable-threshold quantizer, forward path).
// q = POT[max i : t > (a_w[i-1]+a_w[i])/2], default POT[0]; POT = [-8..7].
// One block per weight row.
// ---------------------------------------------------------------------------
__global__ __launch_bounds__(256) void wq_kernel(
    const float* __restrict__ w, const float* __restrict__ alpha,
    const float* __restrict__ beta, const float* __restrict__ a_w,
    u16* __restrict__ qw, float* __restrict__ Sw)
{
  __shared__ float red[256];
  const int row = blockIdx.x;
  const int t = threadIdx.x;
  const float al = alpha[0];
  const float be = beta[0];
  float th[15];
  #pragma unroll
  for (int i = 0; i < 15; ++i) th[i] = 0.5f * (a_w[i] + a_w[i + 1]);

  float qsum = 0.f;
  #pragma unroll
  for (int c = 0; c < 4; ++c) {
    int e = c * 1024 + t * 4;
    float4 v = *(const float4*)(w + (size_t)row * HD + e);
    float vv[4] = {v.x, v.y, v.z, v.w};
    u16 st[4];
    #pragma unroll
    for (int k = 0; k < 4; ++k) {
      float xv = vv[k] + be;
      float tq = xv / al;
      tq = fminf(fmaxf(tq, -8.f), 7.f);
      float qq = -8.f;
      #pragma unroll
      for (int i = 0; i < 15; ++i) qq = (tq > th[i]) ? (float)(i - 7) : qq;
      qsum += qq;
      st[k] = (u16)(__float_as_uint(qq) >> 16);
    }
    *(ushort4*)(qw + (size_t)row * HD + e) = make_ushort4(st[0], st[1], st[2], st[3]);
  }

  red[t] = qsum;
  __syncthreads();
  for (int o = 128; o > 0; o >>= 1) {
    if (t < o) red[t] += red[t + o];
    __syncthreads();
  }
  if (t == 0) Sw[row] = red[0];
}

// ---------------------------------------------------------------------------
// Kernel 3: bf16 MFMA GEMM on integer q-values (exact), m97 structure:
// 128x128 tile, BK=32, 4 waves (2x2), 4x4 16x16x32 frags/wave,
// global_load_lds width 16, 2 barriers per K-step.
// out[m,n] = aa*aw*S - aa*bw*Sx[m] - aw*ba*Sw[n] + K*ba*bw + bias[n]
// ---------------------------------------------------------------------------
#define BM 128
#define BN 128
#define BK 32

__device__ inline void gload_lds16(const void* g, void* l) {
  __builtin_amdgcn_global_load_lds(
      (__attribute__((address_space(1))) void*)((void*)g),
      (__attribute__((address_space(3))) void*)(l), 16, 0, 0);
}

__global__ __launch_bounds__(256) void gemm_qq(
    const u16* __restrict__ qx, const u16* __restrict__ qw,
    const float* __restrict__ bias, const float* __restrict__ Sx,
    const float* __restrict__ Sw,
    const float* __restrict__ p_aa, const float* __restrict__ p_ba,
    const float* __restrict__ p_aw, const float* __restrict__ p_bw,
    float* __restrict__ out, int M, int N, int K)
{
  __shared__ u16 As[BM * BK];
  __shared__ u16 Bs[BN * BK];
  const int tid = threadIdx.x;
  const int lane = tid & 63;
  const int w = tid >> 6;
  const int wr = w >> 1, wc = w & 1;
  const int bn = blockIdx.x, bm = blockIdx.y;

  const size_t baseA = (size_t)(bm * BM) * K;
  const size_t baseB = (size_t)(bn * BN) * K;

  // staging geometry: chunk ci = j*256 + tid covers LDS bytes [ci*16, ci*16+16)
  // == tile row ci>>2, elems (ci&3)*8 .. +8  (row-major [128][32] bf16)
  int rS[2], cS[2];
  #pragma unroll
  for (int j = 0; j < 2; ++j) {
    int ci = j * 256 + tid;
    rS[j] = ci >> 2;
    cS[j] = (ci & 3) * 8;
  }

  f32x4 acc[4][4] = {};

  const int nk = K / BK;
  for (int kt = 0; kt < nk; ++kt) {
    const int k0 = kt * BK;
    #pragma unroll
    for (int j = 0; j < 2; ++j) {
      const u16* gA = qx + baseA + (size_t)rS[j] * K + k0 + cS[j];
      const u16* gB = qw + baseB + (size_t)rS[j] * K + k0 + cS[j];
      u16* lA = (u16*)As + j * 2048 + w * 512;  // wave-uniform base (bytes: j*4096+w*1024)
      u16* lB = (u16*)Bs + j * 2048 + w * 512;
      gload_lds16(gA, lA);
      gload_lds16(gB, lB);
    }
    __syncthreads();   // drains vmcnt -> staged data visible

    s16x8 a[4], b[4];
    const int kread = (lane >> 4) * 8;
    #pragma unroll
    for (int m = 0; m < 4; ++m)
      a[m] = *(const s16x8*)(As + (wr * 64 + m * 16 + (lane & 15)) * BK + kread);
    #pragma unroll
    for (int n = 0; n < 4; ++n)
      b[n] = *(const s16x8*)(Bs + (wc * 64 + n * 16 + (lane & 15)) * BK + kread);

    #pragma unroll
    for (int m = 0; m < 4; ++m)
      #pragma unroll
      for (int n = 0; n < 4; ++n)
        acc[m][n] = __builtin_amdgcn_mfma_f32_16x16x32_bf16(a[m], b[n], acc[m][n], 0, 0, 0);
    __syncthreads();   // compute done, safe to overwrite LDS next iter
  }

  const float aa = p_aa[0], ba = p_ba[0], aw = p_aw[0], bw = p_bw[0];
  const float scale = aa * aw;
  const float rowmul = -aa * bw;
  const float colmul = -aw * ba;
  const float cterm = (float)K * ba * bw;

  #pragma unroll
  for (int n = 0; n < 4; ++n) {
    int col = bn * BN + wc * 64 + n * 16 + (lane & 15);
    float colc = bias[col] + colmul * Sw[col] + cterm;
    #pragma unroll
    for (int m = 0; m < 4; ++m) {
      int row0 = bm * BM + wr * 64 + m * 16 + ((lane >> 4) << 2);
      #pragma unroll
      for (int j2 = 0; j2 < 4; ++j2) {
        int row = row0 + j2;
        out[(size_t)row * N + col] = acc[m][n][j2] * scale + rowmul * Sx[row] + colc;
      }
    }
  }
}

// ---------------------------------------------------------------------------
extern "C" void kernel_launch(void* const* d_in, const int* in_sizes, int n_in,
                              void* d_out, int out_size, void* d_ws, size_t ws_size,
                              hipStream_t stream) {
  const float* x       = (const float*)d_in[0];
  const float* wgt     = (const float*)d_in[1];
  const float* bias    = (const float*)d_in[2];
  const float* alpha_a = (const float*)d_in[3];
  const float* beta_a  = (const float*)d_in[4];
  const float* alpha_w = (const float*)d_in[5];
  const float* beta_w  = (const float*)d_in[6];
  const float* a_w     = (const float*)d_in[7];

  const int K = HD;                 // 4096
  const int M = in_sizes[0] / K;    // 8192 rows of x (B*S)
  const int N = in_sizes[1] / K;    // 4096 output features

  char* ws = (char*)d_ws;
  u16* qx = (u16*)ws;                                     // M*K bf16
  u16* qw = (u16*)(ws + (size_t)M * K * 2);               // N*K bf16
  float* Sx = (float*)(ws + (size_t)M * K * 2 + (size_t)N * K * 2);
  float* Sw = Sx + M;

  fwht_actq<<<M, 256, 0, stream>>>(x, alpha_a, beta_a, qx, Sx);
  wq_kernel<<<N, 256, 0, stream>>>(wgt, alpha_w, beta_w, a_w, qw, Sw);

  dim3 grid(N / BN, M / BM);
  gemm_qq<<<grid, 256, 0, stream>>>(qx, qw, bias, Sx, Sw,
                                    alpha_a, beta_a, alpha_w, beta_w,
                                    (float*)d_out, M, N, K);
}

// Round 2
// 367.476 us; speedup vs baseline: 1.3907x; 1.3907x over previous
//
#include <hip/hip_runtime.h>
#include <hip/hip_bf16.h>
#include <stdint.h>

typedef short  s16x8 __attribute__((ext_vector_type(8)));
typedef float  f32x4 __attribute__((ext_vector_type(4)));
typedef unsigned short u16;

#define HD 4096   // Hadamard / K dimension

// ---------------------------------------------------------------------------
// Kernel 1: row-wise FWHT (== x @ H for symmetric Sylvester H) + act fake-quant
// ---------------------------------------------------------------------------
__global__ __launch_bounds__(256) void fwht_actq(
    const float* __restrict__ x, const float* __restrict__ alpha,
    const float* __restrict__ beta, u16* __restrict__ qx,
    float* __restrict__ Sx)
{
  __shared__ float s[HD];
  const int row = blockIdx.x;
  const int t = threadIdx.x;

  const float4* xin = (const float4*)(x + (size_t)row * HD);
  float4* s4 = (float4*)s;
  #pragma unroll
  for (int c = 0; c < 4; ++c) s4[c * 256 + t] = xin[c * 256 + t];
  __syncthreads();

  for (int h = 1; h < HD; h <<= 1) {
    #pragma unroll
    for (int p = 0; p < 8; ++p) {
      int pid = p * 256 + t;
      int i = ((pid & ~(h - 1)) << 1) | (pid & (h - 1));
      int j = i + h;
      float a = s[i], b = s[j];
      s[i] = a + b;
      s[j] = a - b;
    }
    __syncthreads();
  }

  const float al = alpha[0];
  const float be = beta[0];
  float qsum = 0.f;
  #pragma unroll
  for (int c = 0; c < 4; ++c) {
    int e = c * 1024 + t * 4;
    float4 v = *(const float4*)(s + e);
    u16 st[4];
    float vv[4] = {v.x, v.y, v.z, v.w};
    #pragma unroll
    for (int k = 0; k < 4; ++k) {
      float xv = vv[k] * 0.015625f + be;
      float tq = xv / al;
      tq = fminf(fmaxf(tq, -8.f), 7.f);
      float qq = rintf(tq);                       // half-to-even == np.round
      qsum += qq;
      st[k] = (u16)(__float_as_uint(qq) >> 16);   // exact bf16 of small int
    }
    *(ushort4*)(qx + (size_t)row * HD + e) = make_ushort4(st[0], st[1], st[2], st[3]);
  }

  __syncthreads();
  s[t] = qsum;
  __syncthreads();
  for (int o = 128; o > 0; o >>= 1) {
    if (t < o) s[t] += s[t + o];
    __syncthreads();
  }
  if (t == 0) Sx[row] = s[0];
}

// ---------------------------------------------------------------------------
// Kernel 2: weight fake-quant (learnable-threshold quantizer, forward path)
// ---------------------------------------------------------------------------
__global__ __launch_bounds__(256) void wq_kernel(
    const float* __restrict__ w, const float* __restrict__ alpha,
    const float* __restrict__ beta, const float* __restrict__ a_w,
    u16* __restrict__ qw, float* __restrict__ Sw)
{
  __shared__ float red[256];
  const int row = blockIdx.x;
  const int t = threadIdx.x;
  const float al = alpha[0];
  const float be = beta[0];
  float th[15];
  #pragma unroll
  for (int i = 0; i < 15; ++i) th[i] = 0.5f * (a_w[i] + a_w[i + 1]);

  float qsum = 0.f;
  #pragma unroll
  for (int c = 0; c < 4; ++c) {
    int e = c * 1024 + t * 4;
    float4 v = *(const float4*)(w + (size_t)row * HD + e);
    float vv[4] = {v.x, v.y, v.z, v.w};
    u16 st[4];
    #pragma unroll
    for (int k = 0; k < 4; ++k) {
      float xv = vv[k] + be;
      float tq = xv / al;
      tq = fminf(fmaxf(tq, -8.f), 7.f);
      float qq = -8.f;
      #pragma unroll
      for (int i = 0; i < 15; ++i) qq = (tq > th[i]) ? (float)(i - 7) : qq;
      qsum += qq;
      st[k] = (u16)(__float_as_uint(qq) >> 16);
    }
    *(ushort4*)(qw + (size_t)row * HD + e) = make_ushort4(st[0], st[1], st[2], st[3]);
  }

  red[t] = qsum;
  __syncthreads();
  for (int o = 128; o > 0; o >>= 1) {
    if (t < o) red[t] += red[t + o];
    __syncthreads();
  }
  if (t == 0) Sw[row] = red[0];
}

// ---------------------------------------------------------------------------
// Kernel 3: 256x256 8-phase pipelined bf16 MFMA GEMM on integer q-values.
//   BK=64 split in 2 k-halves; 8 waves (2M x 4N); 128 KiB LDS, 2 K-tile dbuf.
//   Phase = {ds_read frags | stage 1 half-tile | barrier | lgkm0 |
//            setprio(1) 16 MFMA setprio(0) | [vmcnt(4) at odd phases] | barrier}
//   LDS chunk permutation: 16B chunk (row,kcol) at pos (row>>3)*32+kcol*8+(row&7)
//   -> conflict-free ds_read_b128; global source pre-permuted (linear LDS dest).
// ---------------------------------------------------------------------------
#define LDS_B 32768   // u16 offset of B region (A: [0,32768), B: [32768,65536))

__device__ __forceinline__ void gload_lds16(const void* g, void* l) {
  __builtin_amdgcn_global_load_lds(
      (__attribute__((address_space(1))) void*)((void*)g),
      (__attribute__((address_space(3))) void*)(l), 16, 0, 0);
}

#define STAGE_A(buf, u, kh) do { \
  gload_lds16(gA0 + (size_t)(u) * 64 + (kh) * 32, &lds[(buf)*16384 + (kh)*8192 + wv*512]); \
  gload_lds16(gA1 + (size_t)(u) * 64 + (kh) * 32, &lds[(buf)*16384 + (kh)*8192 + 4096 + wv*512]); \
} while (0)

#define STAGE_B(buf, u, kh) do { \
  gload_lds16(gB0 + (size_t)(u) * 64 + (kh) * 32, &lds[LDS_B + (buf)*16384 + (kh)*8192 + wv*512]); \
  gload_lds16(gB1 + (size_t)(u) * 64 + (kh) * 32, &lds[LDS_B + (buf)*16384 + (kh)*8192 + 4096 + wv*512]); \
} while (0)

#define CPWAIT(n) asm volatile("s_waitcnt vmcnt(" #n ")" ::: "memory")
#define NOSTMT ((void)0)

#define PHASE(p, kk, ch, STAGE_STMT, CP_STMT) do { \
  if ((ch) == 0) { \
    _Pragma("unroll") \
    for (int n = 0; n < 4; ++n) \
      b[n] = *(const s16x8*)&lds[LDS_B + (p)*16384 + (kk)*8192 + posB[n]]; \
  } \
  _Pragma("unroll") \
  for (int i = 0; i < 4; ++i) \
    a[i] = *(const s16x8*)&lds[(p)*16384 + (kk)*8192 + posA[(ch)*4 + i]]; \
  STAGE_STMT; \
  __builtin_amdgcn_sched_barrier(0); \
  __builtin_amdgcn_s_barrier(); \
  asm volatile("s_waitcnt lgkmcnt(0)" ::: "memory"); \
  __builtin_amdgcn_sched_barrier(0); \
  __builtin_amdgcn_s_setprio(1); \
  _Pragma("unroll") \
  for (int i = 0; i < 4; ++i) { \
    _Pragma("unroll") \
    for (int n = 0; n < 4; ++n) \
      acc[(ch)*4 + i][n] = __builtin_amdgcn_mfma_f32_16x16x32_bf16(a[i], b[n], acc[(ch)*4 + i][n], 0, 0, 0); \
  } \
  __builtin_amdgcn_s_setprio(0); \
  __builtin_amdgcn_sched_barrier(0); \
  CP_STMT; \
  __builtin_amdgcn_s_barrier(); \
  __builtin_amdgcn_sched_barrier(0); \
} while (0)

// 4 phases of one K-tile (buf p), staging tile t+1 into buf 1-p.
#define TILEBODY(p, t) do { \
  PHASE(p, 0, 0, STAGE_A(1-(p), (t)+1, 0), NOSTMT); \
  PHASE(p, 0, 1, STAGE_B(1-(p), (t)+1, 0), CPWAIT(4)); \
  PHASE(p, 1, 0, STAGE_A(1-(p), (t)+1, 1), NOSTMT); \
  PHASE(p, 1, 1, STAGE_B(1-(p), (t)+1, 1), CPWAIT(4)); \
} while (0)

#define TILELAST(p) do { \
  PHASE(p, 0, 0, NOSTMT, NOSTMT); \
  PHASE(p, 0, 1, NOSTMT, CPWAIT(0)); \
  PHASE(p, 1, 0, NOSTMT, NOSTMT); \
  PHASE(p, 1, 1, NOSTMT, NOSTMT); \
} while (0)

__global__ __launch_bounds__(512, 2) void gemm_qq(
    const u16* __restrict__ qx, const u16* __restrict__ qw,
    const float* __restrict__ bias, const float* __restrict__ Sx,
    const float* __restrict__ Sw,
    const float* __restrict__ p_aa, const float* __restrict__ p_ba,
    const float* __restrict__ p_aw, const float* __restrict__ p_bw,
    float* __restrict__ out, int M, int N, int K)
{
  __shared__ u16 lds[65536];   // 128 KiB
  const int tid  = threadIdx.x;
  const int lane = tid & 63;
  const int wv   = tid >> 6;       // wave 0..7
  const int wm   = wv >> 2;        // 0..1 (M half)
  const int wn   = wv & 3;         // 0..3 (N quarter)
  const int kcol = lane >> 4;      // 0..3

  // T1: bijective XCD swizzle (512 blocks, 8 XCDs, 64 per XCD)
  const int bid  = blockIdx.x;
  const int wgid = (bid & 7) * 64 + (bid >> 3);
  const int bm   = wgid >> 4;      // 0..31
  const int bn   = wgid & 15;      // 0..15

  // ds_read positions (u16 units within one 16KiB half), chunk-permuted
  int posA[8], posB[4];
  #pragma unroll
  for (int fm = 0; fm < 8; ++fm) {
    int row = wm * 128 + fm * 16 + (lane & 15);
    posA[fm] = (((row >> 3) * 32) + kcol * 8 + (row & 7)) * 8;
  }
  #pragma unroll
  for (int n = 0; n < 4; ++n) {
    int col = wn * 64 + n * 16 + (lane & 15);
    posB[n] = (((col >> 3) * 32) + kcol * 8 + (col & 7)) * 8;
  }

  // staging global sources, pre-permuted so linear LDS dest lands swizzled:
  // LDS pos = j*512 + tid  ->  logical row = (j*16 + (tid>>5))*8 + (tid&7),
  //                            kcol = (tid>>3)&3
  const int rs0 = ((tid >> 5)) * 8 + (tid & 7);
  const int rs1 = (16 + (tid >> 5)) * 8 + (tid & 7);
  const int kcs = ((tid >> 3) & 3) * 8;
  const u16* gA0 = qx + (size_t)(bm * 256 + rs0) * K + kcs;
  const u16* gA1 = qx + (size_t)(bm * 256 + rs1) * K + kcs;
  const u16* gB0 = qw + (size_t)(bn * 256 + rs0) * K + kcs;
  const u16* gB1 = qw + (size_t)(bn * 256 + rs1) * K + kcs;

  f32x4 acc[8][4] = {};
  s16x8 a[4], b[4];

  // prologue: stage all 4 halves of tile 0 (issue order: Ak0, Bk0, Ak1, Bk1)
  STAGE_A(0, 0, 0);
  STAGE_B(0, 0, 0);
  STAGE_A(0, 0, 1);
  STAGE_B(0, 0, 1);
  CPWAIT(4);                       // k-half0 of tile 0 complete
  __builtin_amdgcn_sched_barrier(0);
  __builtin_amdgcn_s_barrier();
  __builtin_amdgcn_sched_barrier(0);

  // main loop: NT = 64 K-tiles (K = 4096, BK = 64)
  for (int t = 0; t < 62; t += 2) {
    TILEBODY(0, t);
    TILEBODY(1, t + 1);
  }
  TILEBODY(0, 62);
  TILELAST(1);

  // epilogue: out = aa*aw*S - aa*bw*Sx[m] - aw*ba*Sw[n] + K*ba*bw + bias[n]
  const float aa = p_aa[0], ba = p_ba[0], aw = p_aw[0], bw = p_bw[0];
  const float scale  = aa * aw;
  const float rowmul = -aa * bw;
  const float colmul = -aw * ba;
  const float cterm  = (float)K * ba * bw;

  #pragma unroll
  for (int n = 0; n < 4; ++n) {
    const int col = bn * 256 + wn * 64 + n * 16 + (lane & 15);
    const float colc = bias[col] + colmul * Sw[col] + cterm;
    #pragma unroll
    for (int fm = 0; fm < 8; ++fm) {
      const int row0 = bm * 256 + wm * 128 + fm * 16 + ((lane >> 4) << 2);
      #pragma unroll
      for (int j2 = 0; j2 < 4; ++j2) {
        const int row = row0 + j2;
        out[(size_t)row * N + col] = acc[fm][n][j2] * scale + rowmul * Sx[row] + colc;
      }
    }
  }
}

// ---------------------------------------------------------------------------
extern "C" void kernel_launch(void* const* d_in, const int* in_sizes, int n_in,
                              void* d_out, int out_size, void* d_ws, size_t ws_size,
                              hipStream_t stream) {
  const float* x       = (const float*)d_in[0];
  const float* wgt     = (const float*)d_in[1];
  const float* bias    = (const float*)d_in[2];
  const float* alpha_a = (const float*)d_in[3];
  const float* beta_a  = (const float*)d_in[4];
  const float* alpha_w = (const float*)d_in[5];
  const float* beta_w  = (const float*)d_in[6];
  const float* a_w     = (const float*)d_in[7];

  const int K = HD;                 // 4096
  const int M = in_sizes[0] / K;    // 8192
  const int N = in_sizes[1] / K;    // 4096

  char* ws = (char*)d_ws;
  u16* qx = (u16*)ws;                                     // M*K bf16
  u16* qw = (u16*)(ws + (size_t)M * K * 2);               // N*K bf16
  float* Sx = (float*)(ws + (size_t)M * K * 2 + (size_t)N * K * 2);
  float* Sw = Sx + M;

  fwht_actq<<<M, 256, 0, stream>>>(x, alpha_a, beta_a, qx, Sx);
  wq_kernel<<<N, 256, 0, stream>>>(wgt, alpha_w, beta_w, a_w, qw, Sw);

  const int nwg = (N / 256) * (M / 256);   // 16 * 32 = 512, divisible by 8
  gemm_qq<<<nwg, 512, 0, stream>>>(qx, qw, bias, Sx, Sw,
                                   alpha_a, beta_a, alpha_w, beta_w,
                                   (float*)d_out, M, N, K);
}

// Round 4
// 250.701 us; speedup vs baseline: 2.0385x; 1.4658x over previous
//
#include <hip/hip_runtime.h>
#include <hip/hip_bf16.h>
#include <stdint.h>

typedef int    i32x4 __attribute__((ext_vector_type(4)));
typedef unsigned char u8;

#define HD 4096   // Hadamard / K dimension (elements == bytes for int8)

// ---------------------------------------------------------------------------
// Kernel 1: row-wise FWHT (== x @ H for symmetric Sylvester H) + act fake-quant
// q = rint(clip((xr/64 + beta)/alpha, -8, 7)) stored as int8 (exact),
// plus per-row sum of q for the beta-correction epilogue terms.
// ---------------------------------------------------------------------------
__global__ __launch_bounds__(256) void fwht_actq(
    const float* __restrict__ x, const float* __restrict__ alpha,
    const float* __restrict__ beta, u8* __restrict__ qx,
    float* __restrict__ Sx)
{
  __shared__ float s[HD];
  const int row = blockIdx.x;
  const int t = threadIdx.x;

  const float4* xin = (const float4*)(x + (size_t)row * HD);
  float4* s4 = (float4*)s;
  #pragma unroll
  for (int c = 0; c < 4; ++c) s4[c * 256 + t] = xin[c * 256 + t];
  __syncthreads();

  for (int h = 1; h < HD; h <<= 1) {
    #pragma unroll
    for (int p = 0; p < 8; ++p) {
      int pid = p * 256 + t;
      int i = ((pid & ~(h - 1)) << 1) | (pid & (h - 1));
      int j = i + h;
      float a = s[i], b = s[j];
      s[i] = a + b;
      s[j] = a - b;
    }
    __syncthreads();
  }

  const float al = alpha[0];
  const float be = beta[0];
  float qsum = 0.f;
  int* qx32 = (int*)(qx + (size_t)row * HD);
  #pragma unroll
  for (int c = 0; c < 4; ++c) {
    int e = c * 1024 + t * 4;
    float4 v = *(const float4*)(s + e);
    float vv[4] = {v.x, v.y, v.z, v.w};
    int pk = 0;
    #pragma unroll
    for (int k = 0; k < 4; ++k) {
      float xv = vv[k] * 0.015625f + be;
      float tq = xv / al;
      tq = fminf(fmaxf(tq, -8.f), 7.f);
      float qq = rintf(tq);                // half-to-even == np.round
      qsum += qq;
      pk |= ((int)qq & 0xFF) << (k * 8);
    }
    qx32[c * 256 + t] = pk;
  }

  __syncthreads();
  s[t] = qsum;
  __syncthreads();
  for (int o = 128; o > 0; o >>= 1) {
    if (t < o) s[t] += s[t + o];
    __syncthreads();
  }
  if (t == 0) Sx[row] = s[0];
}

// ---------------------------------------------------------------------------
// Kernel 2: weight fake-quant (learnable-threshold quantizer, forward path)
// ---------------------------------------------------------------------------
__global__ __launch_bounds__(256) void wq_kernel(
    const float* __restrict__ w, const float* __restrict__ alpha,
    const float* __restrict__ beta, const float* __restrict__ a_w,
    u8* __restrict__ qw, float* __restrict__ Sw)
{
  __shared__ float red[256];
  const int row = blockIdx.x;
  const int t = threadIdx.x;
  const float al = alpha[0];
  const float be = beta[0];
  float th[15];
  #pragma unroll
  for (int i = 0; i < 15; ++i) th[i] = 0.5f * (a_w[i] + a_w[i + 1]);

  float qsum = 0.f;
  int* qw32 = (int*)(qw + (size_t)row * HD);
  #pragma unroll
  for (int c = 0; c < 4; ++c) {
    int e = c * 1024 + t * 4;
    float4 v = *(const float4*)(w + (size_t)row * HD + e);
    float vv[4] = {v.x, v.y, v.z, v.w};
    int pk = 0;
    #pragma unroll
    for (int k = 0; k < 4; ++k) {
      float xv = vv[k] + be;
      float tq = xv / al;
      tq = fminf(fmaxf(tq, -8.f), 7.f);
      float qq = -8.f;
      #pragma unroll
      for (int i = 0; i < 15; ++i) qq = (tq > th[i]) ? (float)(i - 7) : qq;
      qsum += qq;
      pk |= ((int)qq & 0xFF) << (k * 8);
    }
    qw32[c * 256 + t] = pk;
  }

  red[t] = qsum;
  __syncthreads();
  for (int o = 128; o > 0; o >>= 1) {
    if (t < o) red[t] += red[t + o];
    __syncthreads();
  }
  if (t == 0) Sw[row] = red[0];
}

// ---------------------------------------------------------------------------
// Kernel 3: 256x256 8-phase pipelined INT8 MFMA GEMM (exact q math).
//   R2's verified sync skeleton, BK=128 bytes (2 k-halves of 64), 8 waves
//   (2M x 4N), 128 KiB LDS, 2 K-tile dbuf, mfma_i32_16x16x64_i8 (K=64/MFMA).
//   Phase = {ds_read frags | stage 1 half-tile | barrier | lgkm0 |
//            setprio(1) 16 MFMA setprio(0) | [vmcnt(4) at even phases] | barrier}
//   LDS chunk permutation per (buf,kh) 16KiB region: 16B chunk (row,kc) at
//   pos (row>>3)*32 + kc*8 + (row&7)  -> conflict-free ds_read_b128;
//   global source pre-permuted (gload_lds dest stays linear).
// ---------------------------------------------------------------------------
#define LDS_BOFF 65536   // byte offset of B region (A: [0,64K), B: [64K,128K))

__device__ __forceinline__ void gload_lds16(const void* g, void* l) {
  __builtin_amdgcn_global_load_lds(
      (__attribute__((address_space(1))) void*)((void*)g),
      (__attribute__((address_space(3))) void*)(l), 16, 0, 0);
}

// stage one (buf, kh) A half-tile: 256 rows x 64 k-bytes = 16 KiB = 2 gloads
#define STAGE_A(buf, u, kh) do { \
  gload_lds16(gA0 + (size_t)(u) * 128 + (kh) * 64, &lds[(buf)*32768 + (kh)*16384 + wv*1024]); \
  gload_lds16(gA1 + (size_t)(u) * 128 + (kh) * 64, &lds[(buf)*32768 + (kh)*16384 + 8192 + wv*1024]); \
} while (0)

#define STAGE_B(buf, u, kh) do { \
  gload_lds16(gB0 + (size_t)(u) * 128 + (kh) * 64, &lds[LDS_BOFF + (buf)*32768 + (kh)*16384 + wv*1024]); \
  gload_lds16(gB1 + (size_t)(u) * 128 + (kh) * 64, &lds[LDS_BOFF + (buf)*32768 + (kh)*16384 + 8192 + wv*1024]); \
} while (0)

#define CPWAIT(n) asm volatile("s_waitcnt vmcnt(" #n ")" ::: "memory")
#define NOSTMT ((void)0)

#define PHASE(p, kk, ch, STAGE_STMT, CP_STMT) do { \
  if ((ch) == 0) { \
    _Pragma("unroll") \
    for (int n = 0; n < 4; ++n) \
      b[n] = *(const i32x4*)&lds[LDS_BOFF + (p)*32768 + (kk)*16384 + posB[n]]; \
  } \
  _Pragma("unroll") \
  for (int i = 0; i < 4; ++i) \
    a[i] = *(const i32x4*)&lds[(p)*32768 + (kk)*16384 + posA[(ch)*4 + i]]; \
  STAGE_STMT; \
  __builtin_amdgcn_sched_barrier(0); \
  __builtin_amdgcn_s_barrier(); \
  asm volatile("s_waitcnt lgkmcnt(0)" ::: "memory"); \
  __builtin_amdgcn_sched_barrier(0); \
  __builtin_amdgcn_s_setprio(1); \
  _Pragma("unroll") \
  for (int i = 0; i < 4; ++i) { \
    _Pragma("unroll") \
    for (int n = 0; n < 4; ++n) \
      acc[(ch)*4 + i][n] = __builtin_amdgcn_mfma_i32_16x16x64_i8(a[i], b[n], acc[(ch)*4 + i][n], 0, 0, 0); \
  } \
  __builtin_amdgcn_s_setprio(0); \
  __builtin_amdgcn_sched_barrier(0); \
  CP_STMT; \
  __builtin_amdgcn_s_barrier(); \
  __builtin_amdgcn_sched_barrier(0); \
} while (0)

// 4 phases of one K-tile (buf p), staging tile t+1 into buf 1-p.
#define TILEBODY(p, t) do { \
  PHASE(p, 0, 0, STAGE_A(1-(p), (t)+1, 0), NOSTMT); \
  PHASE(p, 0, 1, STAGE_B(1-(p), (t)+1, 0), CPWAIT(4)); \
  PHASE(p, 1, 0, STAGE_A(1-(p), (t)+1, 1), NOSTMT); \
  PHASE(p, 1, 1, STAGE_B(1-(p), (t)+1, 1), CPWAIT(4)); \
} while (0)

#define TILELAST(p) do { \
  PHASE(p, 0, 0, NOSTMT, NOSTMT); \
  PHASE(p, 0, 1, NOSTMT, CPWAIT(0)); \
  PHASE(p, 1, 0, NOSTMT, NOSTMT); \
  PHASE(p, 1, 1, NOSTMT, NOSTMT); \
} while (0)

__global__ __launch_bounds__(512, 2) void gemm_qq(
    const u8* __restrict__ qx, const u8* __restrict__ qw,
    const float* __restrict__ bias, const float* __restrict__ Sx,
    const float* __restrict__ Sw,
    const float* __restrict__ p_aa, const float* __restrict__ p_ba,
    const float* __restrict__ p_aw, const float* __restrict__ p_bw,
    float* __restrict__ out, int M, int N, int K)
{
  __shared__ u8 lds[131072];   // 128 KiB
  const int tid  = threadIdx.x;
  const int lane = tid & 63;
  const int wv   = tid >> 6;       // wave 0..7
  const int wm   = wv >> 2;        // 0..1 (M half)
  const int wn   = wv & 3;         // 0..3 (N quarter)

  // T1: bijective XCD swizzle (512 blocks, 8 XCDs, 64 per XCD)
  const int bid  = blockIdx.x;
  const int wgid = (bid & 7) * 64 + (bid >> 3);
  const int bm   = wgid >> 4;      // 0..31
  const int bn   = wgid & 15;      // 0..15

  // frag read byte-positions within one (buf,kh) 16KiB region, chunk-permuted:
  // frag (row, kc=lane>>4) at chunk pos (row>>3)*32 + kc*8 + (row&7)
  int posA[8], posB[4];
  #pragma unroll
  for (int fm = 0; fm < 8; ++fm) {
    int row = wm * 128 + fm * 16 + (lane & 15);
    posA[fm] = (((row >> 3) * 32) + (lane >> 4) * 8 + (row & 7)) * 16;
  }
  #pragma unroll
  for (int n = 0; n < 4; ++n) {
    int col = wn * 64 + n * 16 + (lane & 15);
    posB[n] = (((col >> 3) * 32) + (lane >> 4) * 8 + (col & 7)) * 16;
  }

  // staging global sources, pre-permuted so linear gload_lds dest lands
  // swizzled: set j chunk c=j*512+tid -> row = j*128+(tid>>5)*8+(tid&7),
  // kc = (tid>>3)&3  (16B at byte offset row*K + kh*64 + kc*16)
  const int rs0 = (tid >> 5) * 8 + (tid & 7);
  const int rs1 = 128 + rs0;
  const int kcs = ((tid >> 3) & 3) * 16;
  const u8* gA0 = qx + (size_t)(bm * 256 + rs0) * K + kcs;
  const u8* gA1 = qx + (size_t)(bm * 256 + rs1) * K + kcs;
  const u8* gB0 = qw + (size_t)(bn * 256 + rs0) * K + kcs;
  const u8* gB1 = qw + (size_t)(bn * 256 + rs1) * K + kcs;

  i32x4 acc[8][4] = {};
  i32x4 a[4], b[4];

  // prologue: stage all 4 halves of tile 0 (Ak0, Bk0, Ak1, Bk1)
  STAGE_A(0, 0, 0);
  STAGE_B(0, 0, 0);
  STAGE_A(0, 0, 1);
  STAGE_B(0, 0, 1);
  CPWAIT(4);                       // k-half0 of tile 0 landed
  __builtin_amdgcn_sched_barrier(0);
  __builtin_amdgcn_s_barrier();
  __builtin_amdgcn_sched_barrier(0);

  // main loop: 32 K-tiles (K = 4096 bytes, BK = 128)
  for (int t = 0; t < 30; t += 2) {
    TILEBODY(0, t);
    TILEBODY(1, t + 1);
  }
  TILEBODY(0, 30);
  TILELAST(1);

  // epilogue: out = aa*aw*S - aa*bw*Sx[m] - aw*ba*Sw[n] + K*ba*bw + bias[n]
  const float aa = p_aa[0], ba = p_ba[0], aw = p_aw[0], bw = p_bw[0];
  const float scale  = aa * aw;
  const float rowmul = -aa * bw;
  const float colmul = -aw * ba;
  const float cterm  = (float)K * ba * bw;

  #pragma unroll
  for (int n = 0; n < 4; ++n) {
    const int col = bn * 256 + wn * 64 + n * 16 + (lane & 15);
    const float colc = bias[col] + colmul * Sw[col] + cterm;
    #pragma unroll
    for (int fm = 0; fm < 8; ++fm) {
      const int row0 = bm * 256 + wm * 128 + fm * 16 + ((lane >> 4) << 2);
      #pragma unroll
      for (int j2 = 0; j2 < 4; ++j2) {
        const int row = row0 + j2;
        out[(size_t)row * N + col] = (float)acc[fm][n][j2] * scale + rowmul * Sx[row] + colc;
      }
    }
  }
}

// ---------------------------------------------------------------------------
extern "C" void kernel_launch(void* const* d_in, const int* in_sizes, int n_in,
                              void* d_out, int out_size, void* d_ws, size_t ws_size,
                              hipStream_t stream) {
  const float* x       = (const float*)d_in[0];
  const float* wgt     = (const float*)d_in[1];
  const float* bias    = (const float*)d_in[2];
  const float* alpha_a = (const float*)d_in[3];
  const float* beta_a  = (const float*)d_in[4];
  const float* alpha_w = (const float*)d_in[5];
  const float* beta_w  = (const float*)d_in[6];
  const float* a_w     = (const float*)d_in[7];

  const int K = HD;                 // 4096
  const int M = in_sizes[0] / K;    // 8192
  const int N = in_sizes[1] / K;    // 4096

  char* ws = (char*)d_ws;
  u8* qx = (u8*)ws;                                   // M*K int8
  u8* qw = (u8*)(ws + (size_t)M * K);                 // N*K int8
  float* Sx = (float*)(ws + (size_t)M * K + (size_t)N * K);
  float* Sw = Sx + M;

  fwht_actq<<<M, 256, 0, stream>>>(x, alpha_a, beta_a, qx, Sx);
  wq_kernel<<<N, 256, 0, stream>>>(wgt, alpha_w, beta_w, a_w, qw, Sw);

  const int nwg = (N / 256) * (M / 256);   // 16 * 32 = 512, divisible by 8
  gemm_qq<<<nwg, 512, 0, stream>>>(qx, qw, bias, Sx, Sw,
                                   alpha_a, beta_a, alpha_w, beta_w,
                                   (float*)d_out, M, N, K);
}